// Round 16
// baseline (81.244 us; speedup 1.0000x reference)
//
#include <hip/hip_runtime.h>
#include <hip/hip_fp16.h>

#define BB 16
#define TT 12
#define NN 10000
#define DD 2
#define EE 320000
#define BT 192              // BB*TT
#define TOT 3840000
#define SLICE 20000         // NN*DD

#define NCH 96              // chunks (2 bt-slots each); 96%8==0 -> XCD-pinnable
#define SLICES 14           // edge slices
#define EPS 22858           // ceil(EE/SLICES); last slice short (guarded)
#define SPATB (NCH*SLICES)  // 1344 gather blocks
#define SPATG (SPATB + BT)  // + 192 stream-role blocks (bid < BT)

// prep roles (pack | eoff only)
#define PACKB 942           // 157 node-groups * 6 slot-groups(32)
#define EOFFB 1250          // EE/256
#define PREPG (PACKB + EOFFB)

// ws float layout (fast path):
//   [8192..8196) accumulators: 0=main 1=temp 2=spat 3=cons ; [8196] counter
// fallback: [0,1536) main, [1536,3072) temporal, [3072,6144) cons(8 parts), [6144..) spatial
#define ACC_F 8192
#define EOFF_BOFF 65536
#define W2_BOFF   2656256   // 65536 + EE*8
#define NEED (W2_BOFF + (size_t)NCH * NN * 2 * 4)

typedef float v2f __attribute__((ext_vector_type(2)));
typedef _Float16 hv2 __attribute__((ext_vector_type(2)));

#if defined(__has_builtin)
#if __has_builtin(__builtin_amdgcn_fdot2)
#define HAVE_FDOT2 1
#endif
#if __has_builtin(__builtin_amdgcn_cvt_scalef32_pk_f16_fp8)
#define HAVE_SCALEF16 1
#endif
#endif

__device__ __forceinline__ __half2 pkh2(float a, float b) {
    auto t = __builtin_amdgcn_cvt_pkrtz(a, b);   // __fp16 ext_vector(2)
    return *reinterpret_cast<__half2*>(&t);
}
__device__ __forceinline__ float dot_acc(__half2 d, float acc) {
#ifdef HAVE_FDOT2
    hv2 dr = *reinterpret_cast<hv2*>(&d);
    return __builtin_amdgcn_fdot2(dr, dr, acc, false);
#else
    float2 f = __half22float2(d);
    return fmaf(f.y, f.y, fmaf(f.x, f.x, acc));
#endif
}
// one fp8-packed slot (u32 = p0,p1,t0,t1) both endpoints -> f32 acc
__device__ __forceinline__ void slot_acc(unsigned a, unsigned b, float& acc) {
#ifdef HAVE_SCALEF16
    auto pa = __builtin_amdgcn_cvt_scalef32_pk_f16_fp8(a, 1.0f, false);
    auto ta = __builtin_amdgcn_cvt_scalef32_pk_f16_fp8(a, 1.0f, true);
    auto pb = __builtin_amdgcn_cvt_scalef32_pk_f16_fp8(b, 1.0f, false);
    auto tb = __builtin_amdgcn_cvt_scalef32_pk_f16_fp8(b, 1.0f, true);
    __half2 hpa = *reinterpret_cast<__half2*>(&pa);
    __half2 hta = *reinterpret_cast<__half2*>(&ta);
    __half2 hpb = *reinterpret_cast<__half2*>(&pb);
    __half2 htb = *reinterpret_cast<__half2*>(&tb);
    __half2 d = __hsub2(__habs2(__hsub2(hpa, hpb)), __habs2(__hsub2(hta, htb)));
#else
    v2f ap = __builtin_amdgcn_cvt_pk_f32_fp8((int)a, false);
    v2f at = __builtin_amdgcn_cvt_pk_f32_fp8((int)a, true);
    v2f bp = __builtin_amdgcn_cvt_pk_f32_fp8((int)b, false);
    v2f bq = __builtin_amdgcn_cvt_pk_f32_fp8((int)b, true);
    __half2 d = __hsub2(__habs2(__hsub2(pkh2(ap[0], ap[1]), pkh2(bp[0], bp[1]))),
                        __habs2(__hsub2(pkh2(at[0], at[1]), pkh2(bq[0], bq[1]))));
#endif
    acc = dot_acc(d, acc);
}

// ---------------- prep: pack(fp8, chunk-major) | eoff + acc-zero ------------
__global__ __launch_bounds__(256) void prep_kernel(const float* __restrict__ p,
                                                   const float* __restrict__ tg,
                                                   const int* __restrict__ idx,
                                                   char* __restrict__ wsb) {
    float* ws = (float*)wsb;
    int g = blockIdx.x;
    if (g < PACKB) {                                    // ---- pack role
        __shared__ unsigned tile[64][33];
        int ng = g / 6, cg = g % 6;                     // 64-node group, 32-slot group
        int n0 = ng * 64;
        int ln = threadIdx.x & 63, r = threadIdx.x >> 6;
        int n = n0 + ln;
        if (n < NN) {
            for (int sl = r; sl < 32; sl += 4) {
                int bt = cg * 32 + sl;
                size_t e = (size_t)bt * SLICE + (size_t)n * 2;
                float2 pv = *reinterpret_cast<const float2*>(p + e);
                float2 tv = *reinterpret_cast<const float2*>(tg + e);
                int pk = __builtin_amdgcn_cvt_pk_fp8_f32(pv.x, pv.y, 0, false);
                pk = __builtin_amdgcn_cvt_pk_fp8_f32(tv.x, tv.y, pk, true);
                tile[ln][sl] = (unsigned)pk;
            }
        }
        __syncthreads();
        unsigned* w2c = (unsigned*)(wsb + W2_BOFF);
        for (int f = threadIdx.x; f < 2048; f += 256) {
            int c2 = f >> 7, j2 = f & 127;
            int nn2 = j2 >> 1, k2 = j2 & 1;
            int n2 = n0 + nn2;
            if (n2 < NN) {
                int c = cg * 16 + c2;
                w2c[((unsigned)(c * NN + n2) << 1) + k2] = tile[nn2][c2 * 2 + k2];
            }
        }
    } else {                                            // ---- eoff role
        if (g == PACKB && threadIdx.x < 16)             // zero accumulators+counter
            ws[ACC_F + threadIdx.x] = 0.f;
        int e = (g - PACKB) * 256 + threadIdx.x;
        if (e < EE) {
            uint2* eoff = (uint2*)(wsb + EOFF_BOFF);
            eoff[e] = make_uint2((unsigned)idx[e] * 8u,          // LDS byte offsets
                                 (unsigned)idx[EE + e] * 8u);
        }
    }
}

// ---------------- spatial: stream + gather roles, self-finalizing -----------
__global__ __launch_bounds__(1024, 8) void spatial_kernel(const uint2* __restrict__ w2c2,
                                                          const uint2* __restrict__ eoff,
                                                          const float* __restrict__ p,
                                                          const float* __restrict__ tg,
                                                          float* __restrict__ ws,
                                                          float* __restrict__ out) {
    __shared__ uint2 nd[NN];            // 80,000 B (gather role)
    __shared__ float red[64];
    int bid = blockIdx.x;
    int tid = threadIdx.x;
    float* acc = ws + ACC_F;

    if (bid < BT) {                     // ---- stream role: one bt per block
        int bt = bid;
        size_t base = (size_t)bt * SLICE;
        bool inner = (bt % TT) < TT - 1;
        const float4* p4  = (const float4*)(p + base);
        const float4* t4  = (const float4*)(tg + base);
        const float4* pn4 = (const float4*)(p + base + SLICE);
        const float4* tn4 = (const float4*)(tg + base + SLICE);
        float m = 0.f, w = 0.f, cx = 0.f, cy = 0.f;
        for (int j = tid; j < NN / 2; j += 1024) {      // 2 nodes per float4
            float4 pv = p4[j], tv = t4[j];
            m += fabsf(pv.x - tv.x) + fabsf(pv.y - tv.y)
               + fabsf(pv.z - tv.z) + fabsf(pv.w - tv.w);
            cx += (pv.x - tv.x) + (pv.z - tv.z);
            cy += (pv.y - tv.y) + (pv.w - tv.w);
            if (inner) {
                float4 pn = pn4[j], tn = tn4[j];
                float d0 = (pn.x - pv.x) - (tn.x - tv.x);
                float d1 = (pn.y - pv.y) - (tn.y - tv.y);
                float d2 = (pn.z - pv.z) - (tn.z - tv.z);
                float d3 = (pn.w - pv.w) - (tn.w - tv.w);
                w = fmaf(d0, d0, w);
                w = fmaf(d1, d1, w);
                w = fmaf(d2, d2, w);
                w = fmaf(d3, d3, w);
            }
        }
        for (int o = 32; o; o >>= 1) {
            m += __shfl_xor(m, o); w += __shfl_xor(w, o);
            cx += __shfl_xor(cx, o); cy += __shfl_xor(cy, o);
        }
        int wid = tid >> 6;
        if ((tid & 63) == 0) {
            red[wid] = m; red[16 + wid] = w; red[32 + wid] = cx; red[48 + wid] = cy;
        }
        __syncthreads();
        if (tid == 0) {
            float M = 0, W = 0, CX = 0, CY = 0;
            for (int k = 0; k < 16; ++k) {
                M += red[k]; W += red[16 + k]; CX += red[32 + k]; CY += red[48 + k];
            }
            atomicAdd(acc + 0, M);
            atomicAdd(acc + 1, W);
            atomicAdd(acc + 3, CX * CX + CY * CY);
        }
    } else {                            // ---- gather role
        int gb = bid - BT;
        int c = gb % NCH;               // chunk; same-c blocks land on XCD c%8
        int s = gb / NCH;               // edge slice
        const uint4* src4 = (const uint4*)(w2c2 + (size_t)c * NN);
        uint4* nd4 = (uint4*)nd;
        for (int i = tid; i < NN / 2; i += 1024)
            nd4[i] = src4[i];
        __syncthreads();

        const char* ndb = (const char*)nd;
        int e = s * EPS + tid;
        int eend = (s + 1) * EPS;
        if (eend > EE) eend = EE;
        float acc0 = 0.f, acc1 = 0.f;
        while (e + 1024 < eend) {       // 2 edges per iter
            uint2 o1 = eoff[e], o2 = eoff[e + 1024];
            uint2 A1 = *(const uint2*)(ndb + o1.x);
            uint2 B1 = *(const uint2*)(ndb + o1.y);
            uint2 A2 = *(const uint2*)(ndb + o2.x);
            uint2 B2 = *(const uint2*)(ndb + o2.y);
            slot_acc(A1.x, B1.x, acc0);
            slot_acc(A1.y, B1.y, acc1);
            slot_acc(A2.x, B2.x, acc0);
            slot_acc(A2.y, B2.y, acc1);
            e += 2048;
        }
        if (e < eend) {
            uint2 o = eoff[e];
            uint2 A = *(const uint2*)(ndb + o.x);
            uint2 B = *(const uint2*)(ndb + o.y);
            slot_acc(A.x, B.x, acc0);
            slot_acc(A.y, B.y, acc1);
        }
        float a = acc0 + acc1;
        for (int o = 32; o; o >>= 1) a += __shfl_xor(a, o);
        if ((tid & 63) == 0) red[tid >> 6] = a;
        __syncthreads();
        if (tid == 0) {
            float t = 0.f;
            for (int k = 0; k < 16; ++k) t += red[k];
            atomicAdd(acc + 2, t);
        }
    }

    // ---- completion: last block finalizes
    if (tid == 0) {
        __threadfence();
        unsigned done = atomicAdd((unsigned*)(acc + 4), 1u);
        if (done == SPATG - 1) {
            __threadfence();
            float A  = atomicAdd(acc + 0, 0.f);
            float B2 = atomicAdd(acc + 1, 0.f);
            float S  = atomicAdd(acc + 2, 0.f);
            float C  = atomicAdd(acc + 3, 0.f);
            float mainl = A / (float)TOT;
            float temp  = B2 / (float)(BB * (TT - 1) * NN * DD);
            float spat  = S / ((float)BT * (float)EE * (float)DD);
            float cons  = C / (float)(BT * DD);
            out[0] = mainl + 0.1f * spat + 0.05f * temp + 0.02f * cons;
            out[1] = mainl; out[2] = spat; out[3] = temp; out[4] = cons;
        }
    }
}

// ================= fallback path (ws too small) =============================
__global__ __launch_bounds__(256) void stream_fb(const float* __restrict__ p,
                                                 const float* __restrict__ tg,
                                                 float* __restrict__ ws) {
    int b = blockIdx.x;
    int bt = b >> 3, part = b & 7;
    int tt = bt % TT;
    size_t base = (size_t)bt * SLICE;
    bool inner = (tt < TT - 1);
    float m = 0.f, w = 0.f, c = 0.f;
    int j0 = part * 2500;
    for (int j = j0 + threadIdx.x; j < j0 + 2500; j += 256) {
        size_t jj = base + j;
        float pv = p[jj], tv = tg[jj];
        m += fabsf(pv - tv);
        c += pv - tv;
        if (inner) {
            float pn = p[jj + SLICE], tn = tg[jj + SLICE];
            float dd = (pn - pv) - (tn - tv);
            w += dd * dd;
        }
    }
    for (int o = 32; o >= 2; o >>= 1) {
        m += __shfl_xor(m, o); w += __shfl_xor(w, o); c += __shfl_xor(c, o);
    }
    m += __shfl_xor(m, 1);
    w += __shfl_xor(w, 1);
    __shared__ float sm[4], sw[4], s0[4], s1[4];
    int wid = threadIdx.x >> 6, lane = threadIdx.x & 63;
    if (lane == 0) { sm[wid] = m; sw[wid] = w; s0[wid] = c; }
    if (lane == 1) { s1[wid] = c; }
    __syncthreads();
    if (threadIdx.x == 0) {
        float a = 0, bv = 0, c0 = 0, c1 = 0;
        for (int k = 0; k < 4; k++) { a += sm[k]; bv += sw[k]; c0 += s0[k]; c1 += s1[k]; }
        ws[b] = a; ws[1536 + b] = bv;
        ws[3072 + 2 * b] = c0; ws[3072 + 2 * b + 1] = c1;
    }
}

__global__ __launch_bounds__(256) void spatial_fb(const float* __restrict__ p,
                                                  const float* __restrict__ tg,
                                                  const int* __restrict__ idx,
                                                  float* __restrict__ ws) {
    int lane = threadIdx.x & 63;
    int wave = (blockIdx.x * 256 + threadIdx.x) >> 6;
    float s = 0.f;
    for (int e = wave; e < EE; e += 2048 * 4) {
        int sn = idx[e] * DD, dn = idx[EE + e] * DD;
        for (int bt = lane; bt < BT; bt += 64) {
            size_t base = (size_t)bt * SLICE;
            float2 ps = *reinterpret_cast<const float2*>(p + base + sn);
            float2 pd = *reinterpret_cast<const float2*>(p + base + dn);
            float2 ts = *reinterpret_cast<const float2*>(tg + base + sn);
            float2 td = *reinterpret_cast<const float2*>(tg + base + dn);
            float d0 = fabsf(ps.x - pd.x) - fabsf(ts.x - td.x);
            float d1 = fabsf(ps.y - pd.y) - fabsf(ts.y - td.y);
            s = fmaf(d0, d0, s);
            s = fmaf(d1, d1, s);
        }
    }
    for (int o = 32; o; o >>= 1) s += __shfl_xor(s, o);
    __shared__ float sv[4];
    if (lane == 0) sv[threadIdx.x >> 6] = s;
    __syncthreads();
    if (threadIdx.x == 0) ws[6144 + blockIdx.x] = sv[0] + sv[1] + sv[2] + sv[3];
}

__global__ __launch_bounds__(1024) void finalize_fb(const float* __restrict__ ws,
                                                    float* __restrict__ out) {
    int tid = threadIdx.x;
    float a = 0, bv = 0, sp = 0, cq = 0;
    for (int k = tid; k < 1536; k += 1024) { a += ws[k]; bv += ws[1536 + k]; }
    for (int k = tid; k < 2048; k += 1024) sp += ws[6144 + k];
    if (tid < BT * DD) {
        int bt = tid >> 1, par = tid & 1;
        float cs = 0;
        for (int part = 0; part < 8; ++part)
            cs += ws[3072 + ((bt * 8 + part) << 1) + par];
        cq = cs * cs;
    }
    for (int o = 32; o; o >>= 1) {
        a += __shfl_xor(a, o); bv += __shfl_xor(bv, o);
        sp += __shfl_xor(sp, o); cq += __shfl_xor(cq, o);
    }
    __shared__ float ra[16], rb[16], rs[16], rc[16];
    int wid = tid >> 6;
    if ((tid & 63) == 0) { ra[wid] = a; rb[wid] = bv; rs[wid] = sp; rc[wid] = cq; }
    __syncthreads();
    if (tid == 0) {
        float A = 0, B2 = 0, S = 0, C = 0;
        for (int k = 0; k < 16; k++) { A += ra[k]; B2 += rb[k]; S += rs[k]; C += rc[k]; }
        float mainl = A / (float)TOT;
        float temp  = B2 / (float)(BB * (TT - 1) * NN * DD);
        float spat  = S / ((float)BT * (float)EE * (float)DD);
        float cons  = C / (float)(BT * DD);
        out[0] = mainl + 0.1f * spat + 0.05f * temp + 0.02f * cons;
        out[1] = mainl; out[2] = spat; out[3] = temp; out[4] = cons;
    }
}

extern "C" void kernel_launch(void* const* d_in, const int* in_sizes, int n_in,
                              void* d_out, int out_size, void* d_ws, size_t ws_size,
                              hipStream_t stream) {
    const float* p  = (const float*)d_in[0];
    const float* tg = (const float*)d_in[1];
    const int*   ix = (const int*)d_in[2];
    float* out = (float*)d_out;
    char*  wsb = (char*)d_ws;
    float* ws  = (float*)d_ws;

    if (ws_size >= NEED) {
        prep_kernel<<<PREPG, 256, 0, stream>>>(p, tg, ix, wsb);
        spatial_kernel<<<SPATG, 1024, 0, stream>>>((const uint2*)(wsb + W2_BOFF),
                                                   (const uint2*)(wsb + EOFF_BOFF),
                                                   p, tg, ws, out);
    } else {
        stream_fb<<<1536, 256, 0, stream>>>(p, tg, ws);
        spatial_fb<<<2048, 256, 0, stream>>>(p, tg, ix, ws);
        finalize_fb<<<1, 1024, 0, stream>>>(ws, out);
    }
}

// Round 17
// 50.405 us; speedup vs baseline: 1.6118x; 1.6118x over previous
//
#include <hip/hip_runtime.h>
#include <hip/hip_fp16.h>

#define BB 16
#define TT 12
#define NN 10000
#define DD 2
#define EE 320000
#define BT 192              // BB*TT
#define TOT 3840000
#define SLICE 20000         // NN*DD

#define NCH 96              // chunks (2 bt-slots each); 96%8==0 -> XCD-pinnable
#define SLICES 14           // edge slices (1344+192 = 1536 = 3*512 block slots)
#define EPS 22858           // ceil(EE/SLICES); last slice short (guarded)
#define SPATB (NCH*SLICES)  // 1344 gather blocks
#define SPATG (SPATB + BT)  // + 192 stream-role blocks (bid < BT)

// prep roles (pack | eoff only)
#define PACKB 942           // 157 node-groups * 6 slot-groups(32)
#define EOFFB 1250          // EE/256
#define PREPG (PACKB + EOFFB)

// ws float layout (fast path):
//   [0,192)       main partials (per bt)   [1536,1728) temporal partials (per bt)
//   [3072,3456)   cons sums (per bt*2+d)   [6144,6144+SPATB) spatial partials
// fallback: [0,1536) main, [1536,3072) temporal, [3072,6144) cons(8 parts), [6144..) spatial
#define EOFF_BOFF 32768
#define W2_BOFF   2623488   // 32768 + EE*8
#define NEED (W2_BOFF + (size_t)NCH * NN * 2 * 4)

typedef float v2f __attribute__((ext_vector_type(2)));
typedef _Float16 hv2 __attribute__((ext_vector_type(2)));

#if defined(__has_builtin)
#if __has_builtin(__builtin_amdgcn_fdot2)
#define HAVE_FDOT2 1
#endif
#if __has_builtin(__builtin_amdgcn_cvt_scalef32_pk_f16_fp8)
#define HAVE_SCALEF16 1
#endif
#endif

__device__ __forceinline__ __half2 pkh2(float a, float b) {
    auto t = __builtin_amdgcn_cvt_pkrtz(a, b);   // __fp16 ext_vector(2)
    return *reinterpret_cast<__half2*>(&t);
}
__device__ __forceinline__ float dot_acc(__half2 d, float acc) {
#ifdef HAVE_FDOT2
    hv2 dr = *reinterpret_cast<hv2*>(&d);
    return __builtin_amdgcn_fdot2(dr, dr, acc, false);
#else
    float2 f = __half22float2(d);
    return fmaf(f.y, f.y, fmaf(f.x, f.x, acc));
#endif
}
// one fp8-packed slot (u32 = p0,p1,t0,t1) both endpoints -> f32 acc
__device__ __forceinline__ void slot_acc(unsigned a, unsigned b, float& acc) {
#ifdef HAVE_SCALEF16
    auto pa = __builtin_amdgcn_cvt_scalef32_pk_f16_fp8(a, 1.0f, false);  // p0,p1
    auto ta = __builtin_amdgcn_cvt_scalef32_pk_f16_fp8(a, 1.0f, true);   // t0,t1
    auto pb = __builtin_amdgcn_cvt_scalef32_pk_f16_fp8(b, 1.0f, false);
    auto tb = __builtin_amdgcn_cvt_scalef32_pk_f16_fp8(b, 1.0f, true);
    __half2 hpa = *reinterpret_cast<__half2*>(&pa);
    __half2 hta = *reinterpret_cast<__half2*>(&ta);
    __half2 hpb = *reinterpret_cast<__half2*>(&pb);
    __half2 htb = *reinterpret_cast<__half2*>(&tb);
    __half2 d = __hsub2(__habs2(__hsub2(hpa, hpb)), __habs2(__hsub2(hta, htb)));
#else
    v2f ap = __builtin_amdgcn_cvt_pk_f32_fp8((int)a, false);
    v2f at = __builtin_amdgcn_cvt_pk_f32_fp8((int)a, true);
    v2f bp = __builtin_amdgcn_cvt_pk_f32_fp8((int)b, false);
    v2f bq = __builtin_amdgcn_cvt_pk_f32_fp8((int)b, true);
    __half2 d = __hsub2(__habs2(__hsub2(pkh2(ap[0], ap[1]), pkh2(bp[0], bp[1]))),
                        __habs2(__hsub2(pkh2(at[0], at[1]), pkh2(bq[0], bq[1]))));
#endif
    acc = dot_acc(d, acc);
}

// ---------------- prep: pack(fp8, chunk-major) | eoff (byte-prescaled) ------
__global__ __launch_bounds__(256) void prep_kernel(const float* __restrict__ p,
                                                   const float* __restrict__ tg,
                                                   const int* __restrict__ idx,
                                                   char* __restrict__ wsb) {
    int g = blockIdx.x;
    if (g < PACKB) {                                    // ---- pack role
        __shared__ unsigned tile[64][33];
        int ng = g / 6, cg = g % 6;                     // 64-node group, 32-slot group
        int n0 = ng * 64;
        int ln = threadIdx.x & 63, r = threadIdx.x >> 6;
        int n = n0 + ln;
        if (n < NN) {
            for (int sl = r; sl < 32; sl += 4) {
                int bt = cg * 32 + sl;
                size_t e = (size_t)bt * SLICE + (size_t)n * 2;
                float2 pv = *reinterpret_cast<const float2*>(p + e);
                float2 tv = *reinterpret_cast<const float2*>(tg + e);
                int pk = __builtin_amdgcn_cvt_pk_fp8_f32(pv.x, pv.y, 0, false);
                pk = __builtin_amdgcn_cvt_pk_fp8_f32(tv.x, tv.y, pk, true);
                tile[ln][sl] = (unsigned)pk;
            }
        }
        __syncthreads();
        unsigned* w2c = (unsigned*)(wsb + W2_BOFF);
        for (int f = threadIdx.x; f < 2048; f += 256) {
            int c2 = f >> 7, j2 = f & 127;
            int nn2 = j2 >> 1, k2 = j2 & 1;
            int n2 = n0 + nn2;
            if (n2 < NN) {
                int c = cg * 16 + c2;
                w2c[((unsigned)(c * NN + n2) << 1) + k2] = tile[nn2][c2 * 2 + k2];
            }
        }
    } else {                                            // ---- eoff role
        int e = (g - PACKB) * 256 + threadIdx.x;
        if (e < EE) {
            uint2* eoff = (uint2*)(wsb + EOFF_BOFF);
            eoff[e] = make_uint2((unsigned)idx[e] * 8u,          // LDS byte offsets
                                 (unsigned)idx[EE + e] * 8u);
        }
    }
}

// ---------------- spatial: stream blocks first, then gather blocks ----------
__global__ __launch_bounds__(1024, 8) void spatial_kernel(const uint2* __restrict__ w2c2,
                                                          const uint2* __restrict__ eoff,
                                                          const float* __restrict__ p,
                                                          const float* __restrict__ tg,
                                                          float* __restrict__ ws) {
    __shared__ uint2 nd[NN];            // 80,000 B (gather role)
    __shared__ float red[64];
    int bid = blockIdx.x;
    int tid = threadIdx.x;

    if (bid < BT) {                     // ---- stream role: one bt per block
        int bt = bid;
        size_t base = (size_t)bt * SLICE;
        bool inner = (bt % TT) < TT - 1;
        const float4* p4  = (const float4*)(p + base);
        const float4* t4  = (const float4*)(tg + base);
        const float4* pn4 = (const float4*)(p + base + SLICE);
        const float4* tn4 = (const float4*)(tg + base + SLICE);
        float m = 0.f, w = 0.f, cx = 0.f, cy = 0.f;
        for (int j = tid; j < NN / 2; j += 1024) {      // 2 nodes per float4
            float4 pv = p4[j], tv = t4[j];
            m += fabsf(pv.x - tv.x) + fabsf(pv.y - tv.y)
               + fabsf(pv.z - tv.z) + fabsf(pv.w - tv.w);
            cx += (pv.x - tv.x) + (pv.z - tv.z);
            cy += (pv.y - tv.y) + (pv.w - tv.w);
            if (inner) {
                float4 pn = pn4[j], tn = tn4[j];
                float d0 = (pn.x - pv.x) - (tn.x - tv.x);
                float d1 = (pn.y - pv.y) - (tn.y - tv.y);
                float d2 = (pn.z - pv.z) - (tn.z - tv.z);
                float d3 = (pn.w - pv.w) - (tn.w - tv.w);
                w = fmaf(d0, d0, w);
                w = fmaf(d1, d1, w);
                w = fmaf(d2, d2, w);
                w = fmaf(d3, d3, w);
            }
        }
        for (int o = 32; o; o >>= 1) {
            m += __shfl_xor(m, o); w += __shfl_xor(w, o);
            cx += __shfl_xor(cx, o); cy += __shfl_xor(cy, o);
        }
        int wid = tid >> 6;
        if ((tid & 63) == 0) {
            red[wid] = m; red[16 + wid] = w; red[32 + wid] = cx; red[48 + wid] = cy;
        }
        __syncthreads();
        if (tid == 0) {
            float M = 0, W = 0, CX = 0, CY = 0;
            for (int k = 0; k < 16; ++k) {
                M += red[k]; W += red[16 + k]; CX += red[32 + k]; CY += red[48 + k];
            }
            ws[bt] = M;
            ws[1536 + bt] = W;
            ws[3072 + 2 * bt] = CX;
            ws[3072 + 2 * bt + 1] = CY;
        }
        return;
    }

    // ---- gather role
    int gb = bid - BT;
    int c = gb % NCH;                   // chunk; same-c blocks land on XCD c%8
    int s = gb / NCH;                   // edge slice
    const uint4* src4 = (const uint4*)(w2c2 + (size_t)c * NN);
    uint4* nd4 = (uint4*)nd;
    for (int i = tid; i < NN / 2; i += 1024)
        nd4[i] = src4[i];
    __syncthreads();

    const char* ndb = (const char*)nd;
    int e = s * EPS + tid;
    int eend = (s + 1) * EPS;
    if (eend > EE) eend = EE;
    float acc0 = 0.f, acc1 = 0.f;
    while (e + 1024 < eend) {           // 2 edges per iter
        uint2 o1 = eoff[e], o2 = eoff[e + 1024];
        uint2 A1 = *(const uint2*)(ndb + o1.x);
        uint2 B1 = *(const uint2*)(ndb + o1.y);
        uint2 A2 = *(const uint2*)(ndb + o2.x);
        uint2 B2 = *(const uint2*)(ndb + o2.y);
        slot_acc(A1.x, B1.x, acc0);
        slot_acc(A1.y, B1.y, acc1);
        slot_acc(A2.x, B2.x, acc0);
        slot_acc(A2.y, B2.y, acc1);
        e += 2048;
    }
    if (e < eend) {
        uint2 o = eoff[e];
        uint2 A = *(const uint2*)(ndb + o.x);
        uint2 B = *(const uint2*)(ndb + o.y);
        slot_acc(A.x, B.x, acc0);
        slot_acc(A.y, B.y, acc1);
    }
    float acc = acc0 + acc1;
    for (int o = 32; o; o >>= 1) acc += __shfl_xor(acc, o);
    if ((tid & 63) == 0) red[tid >> 6] = acc;
    __syncthreads();
    if (tid == 0) {
        float t = 0.f;
        for (int k = 0; k < 16; ++k) t += red[k];
        ws[6144 + gb] = t;
    }
}

// ---------------- finalize (fast path, compact layout) ----------------------
__global__ __launch_bounds__(1024) void finalize_kernel(const float* __restrict__ ws,
                                                        float* __restrict__ out) {
    int tid = threadIdx.x;
    float a = 0, bv = 0, sp = 0, cq = 0;
    if (tid < BT) { a = ws[tid]; bv = ws[1536 + tid]; }
    for (int k = tid; k < SPATB; k += 1024) sp += ws[6144 + k];
    if (tid < BT * DD) { float cs = ws[3072 + tid]; cq = cs * cs; }
    for (int o = 32; o; o >>= 1) {
        a += __shfl_xor(a, o); bv += __shfl_xor(bv, o);
        sp += __shfl_xor(sp, o); cq += __shfl_xor(cq, o);
    }
    __shared__ float ra[16], rb[16], rs[16], rc[16];
    int wid = tid >> 6;
    if ((tid & 63) == 0) { ra[wid] = a; rb[wid] = bv; rs[wid] = sp; rc[wid] = cq; }
    __syncthreads();
    if (tid == 0) {
        float A = 0, B2 = 0, S = 0, C = 0;
        for (int k = 0; k < 16; k++) { A += ra[k]; B2 += rb[k]; S += rs[k]; C += rc[k]; }
        float mainl = A / (float)TOT;
        float temp  = B2 / (float)(BB * (TT - 1) * NN * DD);
        float spat  = S / ((float)BT * (float)EE * (float)DD);
        float cons  = C / (float)(BT * DD);
        out[0] = mainl + 0.1f * spat + 0.05f * temp + 0.02f * cons;
        out[1] = mainl; out[2] = spat; out[3] = temp; out[4] = cons;
    }
}

// ================= fallback path (ws too small) =============================
__global__ __launch_bounds__(256) void stream_fb(const float* __restrict__ p,
                                                 const float* __restrict__ tg,
                                                 float* __restrict__ ws) {
    int b = blockIdx.x;
    int bt = b >> 3, part = b & 7;
    int tt = bt % TT;
    size_t base = (size_t)bt * SLICE;
    bool inner = (tt < TT - 1);
    float m = 0.f, w = 0.f, c = 0.f;
    int j0 = part * 2500;
    for (int j = j0 + threadIdx.x; j < j0 + 2500; j += 256) {
        size_t jj = base + j;
        float pv = p[jj], tv = tg[jj];
        m += fabsf(pv - tv);
        c += pv - tv;
        if (inner) {
            float pn = p[jj + SLICE], tn = tg[jj + SLICE];
            float dd = (pn - pv) - (tn - tv);
            w += dd * dd;
        }
    }
    for (int o = 32; o >= 2; o >>= 1) {
        m += __shfl_xor(m, o); w += __shfl_xor(w, o); c += __shfl_xor(c, o);
    }
    m += __shfl_xor(m, 1);
    w += __shfl_xor(w, 1);
    __shared__ float sm[4], sw[4], s0[4], s1[4];
    int wid = threadIdx.x >> 6, lane = threadIdx.x & 63;
    if (lane == 0) { sm[wid] = m; sw[wid] = w; s0[wid] = c; }
    if (lane == 1) { s1[wid] = c; }
    __syncthreads();
    if (threadIdx.x == 0) {
        float a = 0, bv = 0, c0 = 0, c1 = 0;
        for (int k = 0; k < 4; k++) { a += sm[k]; bv += sw[k]; c0 += s0[k]; c1 += s1[k]; }
        ws[b] = a; ws[1536 + b] = bv;
        ws[3072 + 2 * b] = c0; ws[3072 + 2 * b + 1] = c1;
    }
}

__global__ __launch_bounds__(256) void spatial_fb(const float* __restrict__ p,
                                                  const float* __restrict__ tg,
                                                  const int* __restrict__ idx,
                                                  float* __restrict__ ws) {
    int lane = threadIdx.x & 63;
    int wave = (blockIdx.x * 256 + threadIdx.x) >> 6;
    float s = 0.f;
    for (int e = wave; e < EE; e += 2048 * 4) {
        int sn = idx[e] * DD, dn = idx[EE + e] * DD;
        for (int bt = lane; bt < BT; bt += 64) {
            size_t base = (size_t)bt * SLICE;
            float2 ps = *reinterpret_cast<const float2*>(p + base + sn);
            float2 pd = *reinterpret_cast<const float2*>(p + base + dn);
            float2 ts = *reinterpret_cast<const float2*>(tg + base + sn);
            float2 td = *reinterpret_cast<const float2*>(tg + base + dn);
            float d0 = fabsf(ps.x - pd.x) - fabsf(ts.x - td.x);
            float d1 = fabsf(ps.y - pd.y) - fabsf(ts.y - td.y);
            s = fmaf(d0, d0, s);
            s = fmaf(d1, d1, s);
        }
    }
    for (int o = 32; o; o >>= 1) s += __shfl_xor(s, o);
    __shared__ float sv[4];
    if (lane == 0) sv[threadIdx.x >> 6] = s;
    __syncthreads();
    if (threadIdx.x == 0) ws[6144 + blockIdx.x] = sv[0] + sv[1] + sv[2] + sv[3];
}

__global__ __launch_bounds__(1024) void finalize_fb(const float* __restrict__ ws,
                                                    float* __restrict__ out) {
    int tid = threadIdx.x;
    float a = 0, bv = 0, sp = 0, cq = 0;
    for (int k = tid; k < 1536; k += 1024) { a += ws[k]; bv += ws[1536 + k]; }
    for (int k = tid; k < 2048; k += 1024) sp += ws[6144 + k];
    if (tid < BT * DD) {
        int bt = tid >> 1, par = tid & 1;
        float cs = 0;
        for (int part = 0; part < 8; ++part)
            cs += ws[3072 + ((bt * 8 + part) << 1) + par];
        cq = cs * cs;
    }
    for (int o = 32; o; o >>= 1) {
        a += __shfl_xor(a, o); bv += __shfl_xor(bv, o);
        sp += __shfl_xor(sp, o); cq += __shfl_xor(cq, o);
    }
    __shared__ float ra[16], rb[16], rs[16], rc[16];
    int wid = tid >> 6;
    if ((tid & 63) == 0) { ra[wid] = a; rb[wid] = bv; rs[wid] = sp; rc[wid] = cq; }
    __syncthreads();
    if (tid == 0) {
        float A = 0, B2 = 0, S = 0, C = 0;
        for (int k = 0; k < 16; k++) { A += ra[k]; B2 += rb[k]; S += rs[k]; C += rc[k]; }
        float mainl = A / (float)TOT;
        float temp  = B2 / (float)(BB * (TT - 1) * NN * DD);
        float spat  = S / ((float)BT * (float)EE * (float)DD);
        float cons  = C / (float)(BT * DD);
        out[0] = mainl + 0.1f * spat + 0.05f * temp + 0.02f * cons;
        out[1] = mainl; out[2] = spat; out[3] = temp; out[4] = cons;
    }
}

extern "C" void kernel_launch(void* const* d_in, const int* in_sizes, int n_in,
                              void* d_out, int out_size, void* d_ws, size_t ws_size,
                              hipStream_t stream) {
    const float* p  = (const float*)d_in[0];
    const float* tg = (const float*)d_in[1];
    const int*   ix = (const int*)d_in[2];
    float* out = (float*)d_out;
    char*  wsb = (char*)d_ws;
    float* ws  = (float*)d_ws;

    if (ws_size >= NEED) {
        prep_kernel<<<PREPG, 256, 0, stream>>>(p, tg, ix, wsb);
        spatial_kernel<<<SPATG, 1024, 0, stream>>>((const uint2*)(wsb + W2_BOFF),
                                                   (const uint2*)(wsb + EOFF_BOFF),
                                                   p, tg, ws);
        finalize_kernel<<<1, 1024, 0, stream>>>(ws, out);
    } else {
        stream_fb<<<1536, 256, 0, stream>>>(p, tg, ws);
        spatial_fb<<<2048, 256, 0, stream>>>(p, tg, ix, ws);
        finalize_fb<<<1, 1024, 0, stream>>>(ws, out);
    }
}

// Round 18
// 48.394 us; speedup vs baseline: 1.6788x; 1.0416x over previous
//
#include <hip/hip_runtime.h>
#include <hip/hip_fp16.h>

#define BB 16
#define TT 12
#define NN 10000
#define DD 2
#define EE 320000
#define BT 192              // BB*TT
#define TOT 3840000
#define SLICE 20000         // NN*DD

#define NCH 96              // chunks (2 bt-slots each); 96%8==0 -> XCD-pinnable
#define SLICES 14           // edge slices (1344+192 = 1536 = 3*512 block slots)
#define EPS 22858           // ceil(EE/SLICES); last slice short (guarded)
#define SPATB (NCH*SLICES)  // 1344 gather blocks
#define SPATG (SPATB + BT)  // + 192 stream-role blocks (bid < BT)

// prep roles (pack | eoff only)
#define PACKB 942           // 157 node-groups * 6 slot-groups(32)
#define EOFFB 1250          // EE/256
#define PREPG (PACKB + EOFFB)

// ws float layout (fast path):
//   [0,192)       main partials (per bt)   [1536,1728) temporal partials (per bt)
//   [3072,3456)   cons sums (per bt*2+d)   [6144,6144+SPATB) spatial partials
// fallback: [0,1536) main, [1536,3072) temporal, [3072,6144) cons(8 parts), [6144..) spatial
#define EOFF_BOFF 32768
#define W2_BOFF   2623488   // 32768 + EE*8
#define NEED (W2_BOFF + (size_t)NCH * NN * 2 * 4)

typedef float v2f __attribute__((ext_vector_type(2)));
typedef _Float16 hv2 __attribute__((ext_vector_type(2)));

#if defined(__has_builtin)
#if __has_builtin(__builtin_amdgcn_fdot2)
#define HAVE_FDOT2 1
#endif
#if __has_builtin(__builtin_amdgcn_cvt_scalef32_pk_f16_fp8)
#define HAVE_SCALEF16 1
#endif
#endif

__device__ __forceinline__ __half2 pkh2(float a, float b) {
    auto t = __builtin_amdgcn_cvt_pkrtz(a, b);   // __fp16 ext_vector(2)
    return *reinterpret_cast<__half2*>(&t);
}
__device__ __forceinline__ float dot_acc(__half2 d, float acc) {
#ifdef HAVE_FDOT2
    hv2 dr = *reinterpret_cast<hv2*>(&d);
    return __builtin_amdgcn_fdot2(dr, dr, acc, false);
#else
    float2 f = __half22float2(d);
    return fmaf(f.y, f.y, fmaf(f.x, f.x, acc));
#endif
}
// one fp8-packed slot (u32 = p0,p1,t0,t1) both endpoints -> f32 acc
__device__ __forceinline__ void slot_acc(unsigned a, unsigned b, float& acc) {
#ifdef HAVE_SCALEF16
    auto pa = __builtin_amdgcn_cvt_scalef32_pk_f16_fp8(a, 1.0f, false);  // p0,p1
    auto ta = __builtin_amdgcn_cvt_scalef32_pk_f16_fp8(a, 1.0f, true);   // t0,t1
    auto pb = __builtin_amdgcn_cvt_scalef32_pk_f16_fp8(b, 1.0f, false);
    auto tb = __builtin_amdgcn_cvt_scalef32_pk_f16_fp8(b, 1.0f, true);
    __half2 hpa = *reinterpret_cast<__half2*>(&pa);
    __half2 hta = *reinterpret_cast<__half2*>(&ta);
    __half2 hpb = *reinterpret_cast<__half2*>(&pb);
    __half2 htb = *reinterpret_cast<__half2*>(&tb);
    __half2 d = __hsub2(__habs2(__hsub2(hpa, hpb)), __habs2(__hsub2(hta, htb)));
#else
    v2f ap = __builtin_amdgcn_cvt_pk_f32_fp8((int)a, false);
    v2f at = __builtin_amdgcn_cvt_pk_f32_fp8((int)a, true);
    v2f bp = __builtin_amdgcn_cvt_pk_f32_fp8((int)b, false);
    v2f bq = __builtin_amdgcn_cvt_pk_f32_fp8((int)b, true);
    __half2 d = __hsub2(__habs2(__hsub2(pkh2(ap[0], ap[1]), pkh2(bp[0], bp[1]))),
                        __habs2(__hsub2(pkh2(at[0], at[1]), pkh2(bq[0], bq[1]))));
#endif
    acc = dot_acc(d, acc);
}

// ---------------- prep: pack(fp8, chunk-major) | eoff (byte-prescaled) ------
__global__ __launch_bounds__(256) void prep_kernel(const float* __restrict__ p,
                                                   const float* __restrict__ tg,
                                                   const int* __restrict__ idx,
                                                   char* __restrict__ wsb) {
    int g = blockIdx.x;
    if (g < PACKB) {                                    // ---- pack role
        __shared__ unsigned tile[64][33];
        int ng = g / 6, cg = g % 6;                     // 64-node group, 32-slot group
        int n0 = ng * 64;
        int ln = threadIdx.x & 63, r = threadIdx.x >> 6;
        int n = n0 + ln;
        if (n < NN) {
            for (int sl = r; sl < 32; sl += 4) {
                int bt = cg * 32 + sl;
                size_t e = (size_t)bt * SLICE + (size_t)n * 2;
                float2 pv = *reinterpret_cast<const float2*>(p + e);
                float2 tv = *reinterpret_cast<const float2*>(tg + e);
                int pk = __builtin_amdgcn_cvt_pk_fp8_f32(pv.x, pv.y, 0, false);
                pk = __builtin_amdgcn_cvt_pk_fp8_f32(tv.x, tv.y, pk, true);
                tile[ln][sl] = (unsigned)pk;
            }
        }
        __syncthreads();
        unsigned* w2c = (unsigned*)(wsb + W2_BOFF);
        for (int f = threadIdx.x; f < 2048; f += 256) {
            int c2 = f >> 7, j2 = f & 127;
            int nn2 = j2 >> 1, k2 = j2 & 1;
            int n2 = n0 + nn2;
            if (n2 < NN) {
                int c = cg * 16 + c2;
                w2c[((unsigned)(c * NN + n2) << 1) + k2] = tile[nn2][c2 * 2 + k2];
            }
        }
    } else {                                            // ---- eoff role
        int e = (g - PACKB) * 256 + threadIdx.x;
        if (e < EE) {
            uint2* eoff = (uint2*)(wsb + EOFF_BOFF);
            eoff[e] = make_uint2((unsigned)idx[e] * 8u,          // LDS byte offsets
                                 (unsigned)idx[EE + e] * 8u);
        }
    }
}

// ---------------- spatial: stream blocks first, then gather blocks ----------
__global__ __launch_bounds__(1024, 8) void spatial_kernel(const uint2* __restrict__ w2c2,
                                                          const uint2* __restrict__ eoff,
                                                          const float* __restrict__ p,
                                                          const float* __restrict__ tg,
                                                          float* __restrict__ ws) {
    __shared__ uint2 nd[NN];            // 80,000 B (gather role)
    __shared__ float red[64];
    int bid = blockIdx.x;
    int tid = threadIdx.x;

    if (bid < BT) {                     // ---- stream role: one bt per block
        int bt = bid;
        size_t base = (size_t)bt * SLICE;
        bool inner = (bt % TT) < TT - 1;
        const float2* p2  = (const float2*)(p + base);
        const float2* t2  = (const float2*)(tg + base);
        const float2* pn2 = (const float2*)(p + base + SLICE);
        const float2* tn2 = (const float2*)(tg + base + SLICE);
        float m = 0.f, w = 0.f, cx = 0.f, cy = 0.f;
        for (int j = tid; j < NN; j += 1024) {
            float2 pv = p2[j], tv = t2[j];
            m += fabsf(pv.x - tv.x) + fabsf(pv.y - tv.y);
            cx += pv.x - tv.x;
            cy += pv.y - tv.y;
            if (inner) {
                float2 pn = pn2[j], tn = tn2[j];
                float d0 = (pn.x - pv.x) - (tn.x - tv.x);
                float d1 = (pn.y - pv.y) - (tn.y - tv.y);
                w = fmaf(d0, d0, w);
                w = fmaf(d1, d1, w);
            }
        }
        for (int o = 32; o; o >>= 1) {
            m += __shfl_xor(m, o); w += __shfl_xor(w, o);
            cx += __shfl_xor(cx, o); cy += __shfl_xor(cy, o);
        }
        int wid = tid >> 6;
        if ((tid & 63) == 0) {
            red[wid] = m; red[16 + wid] = w; red[32 + wid] = cx; red[48 + wid] = cy;
        }
        __syncthreads();
        if (tid == 0) {
            float M = 0, W = 0, CX = 0, CY = 0;
            for (int k = 0; k < 16; ++k) {
                M += red[k]; W += red[16 + k]; CX += red[32 + k]; CY += red[48 + k];
            }
            ws[bt] = M;
            ws[1536 + bt] = W;
            ws[3072 + 2 * bt] = CX;
            ws[3072 + 2 * bt + 1] = CY;
        }
        return;
    }

    // ---- gather role
    int gb = bid - BT;
    int c = gb % NCH;                   // chunk; same-c blocks land on XCD c%8
    int s = gb / NCH;                   // edge slice
    const uint4* src4 = (const uint4*)(w2c2 + (size_t)c * NN);
    uint4* nd4 = (uint4*)nd;
    for (int i = tid; i < NN / 2; i += 1024)
        nd4[i] = src4[i];
    __syncthreads();

    const char* ndb = (const char*)nd;
    int e = s * EPS + tid;
    int eend = (s + 1) * EPS;
    if (eend > EE) eend = EE;
    float acc0 = 0.f, acc1 = 0.f;
    while (e + 1024 < eend) {           // 2 edges per iter
        uint2 o1 = eoff[e], o2 = eoff[e + 1024];
        uint2 A1 = *(const uint2*)(ndb + o1.x);
        uint2 B1 = *(const uint2*)(ndb + o1.y);
        uint2 A2 = *(const uint2*)(ndb + o2.x);
        uint2 B2 = *(const uint2*)(ndb + o2.y);
        slot_acc(A1.x, B1.x, acc0);
        slot_acc(A1.y, B1.y, acc1);
        slot_acc(A2.x, B2.x, acc0);
        slot_acc(A2.y, B2.y, acc1);
        e += 2048;
    }
    if (e < eend) {
        uint2 o = eoff[e];
        uint2 A = *(const uint2*)(ndb + o.x);
        uint2 B = *(const uint2*)(ndb + o.y);
        slot_acc(A.x, B.x, acc0);
        slot_acc(A.y, B.y, acc1);
    }
    float acc = acc0 + acc1;
    for (int o = 32; o; o >>= 1) acc += __shfl_xor(acc, o);
    if ((tid & 63) == 0) red[tid >> 6] = acc;
    __syncthreads();
    if (tid == 0) {
        float t = 0.f;
        for (int k = 0; k < 16; ++k) t += red[k];
        ws[6144 + gb] = t;
    }
}

// ---------------- finalize (fast path, compact layout) ----------------------
__global__ __launch_bounds__(1024) void finalize_kernel(const float* __restrict__ ws,
                                                        float* __restrict__ out) {
    int tid = threadIdx.x;
    float a = 0, bv = 0, sp = 0, cq = 0;
    if (tid < BT) { a = ws[tid]; bv = ws[1536 + tid]; }
    for (int k = tid; k < SPATB; k += 1024) sp += ws[6144 + k];
    if (tid < BT * DD) { float cs = ws[3072 + tid]; cq = cs * cs; }
    for (int o = 32; o; o >>= 1) {
        a += __shfl_xor(a, o); bv += __shfl_xor(bv, o);
        sp += __shfl_xor(sp, o); cq += __shfl_xor(cq, o);
    }
    __shared__ float ra[16], rb[16], rs[16], rc[16];
    int wid = tid >> 6;
    if ((tid & 63) == 0) { ra[wid] = a; rb[wid] = bv; rs[wid] = sp; rc[wid] = cq; }
    __syncthreads();
    if (tid == 0) {
        float A = 0, B2 = 0, S = 0, C = 0;
        for (int k = 0; k < 16; k++) { A += ra[k]; B2 += rb[k]; S += rs[k]; C += rc[k]; }
        float mainl = A / (float)TOT;
        float temp  = B2 / (float)(BB * (TT - 1) * NN * DD);
        float spat  = S / ((float)BT * (float)EE * (float)DD);
        float cons  = C / (float)(BT * DD);
        out[0] = mainl + 0.1f * spat + 0.05f * temp + 0.02f * cons;
        out[1] = mainl; out[2] = spat; out[3] = temp; out[4] = cons;
    }
}

// ================= fallback path (ws too small) =============================
__global__ __launch_bounds__(256) void stream_fb(const float* __restrict__ p,
                                                 const float* __restrict__ tg,
                                                 float* __restrict__ ws) {
    int b = blockIdx.x;
    int bt = b >> 3, part = b & 7;
    int tt = bt % TT;
    size_t base = (size_t)bt * SLICE;
    bool inner = (tt < TT - 1);
    float m = 0.f, w = 0.f, c = 0.f;
    int j0 = part * 2500;
    for (int j = j0 + threadIdx.x; j < j0 + 2500; j += 256) {
        size_t jj = base + j;
        float pv = p[jj], tv = tg[jj];
        m += fabsf(pv - tv);
        c += pv - tv;
        if (inner) {
            float pn = p[jj + SLICE], tn = tg[jj + SLICE];
            float dd = (pn - pv) - (tn - tv);
            w += dd * dd;
        }
    }
    for (int o = 32; o >= 2; o >>= 1) {
        m += __shfl_xor(m, o); w += __shfl_xor(w, o); c += __shfl_xor(c, o);
    }
    m += __shfl_xor(m, 1);
    w += __shfl_xor(w, 1);
    __shared__ float sm[4], sw[4], s0[4], s1[4];
    int wid = threadIdx.x >> 6, lane = threadIdx.x & 63;
    if (lane == 0) { sm[wid] = m; sw[wid] = w; s0[wid] = c; }
    if (lane == 1) { s1[wid] = c; }
    __syncthreads();
    if (threadIdx.x == 0) {
        float a = 0, bv = 0, c0 = 0, c1 = 0;
        for (int k = 0; k < 4; k++) { a += sm[k]; bv += sw[k]; c0 += s0[k]; c1 += s1[k]; }
        ws[b] = a; ws[1536 + b] = bv;
        ws[3072 + 2 * b] = c0; ws[3072 + 2 * b + 1] = c1;
    }
}

__global__ __launch_bounds__(256) void spatial_fb(const float* __restrict__ p,
                                                  const float* __restrict__ tg,
                                                  const int* __restrict__ idx,
                                                  float* __restrict__ ws) {
    int lane = threadIdx.x & 63;
    int wave = (blockIdx.x * 256 + threadIdx.x) >> 6;
    float s = 0.f;
    for (int e = wave; e < EE; e += 2048 * 4) {
        int sn = idx[e] * DD, dn = idx[EE + e] * DD;
        for (int bt = lane; bt < BT; bt += 64) {
            size_t base = (size_t)bt * SLICE;
            float2 ps = *reinterpret_cast<const float2*>(p + base + sn);
            float2 pd = *reinterpret_cast<const float2*>(p + base + dn);
            float2 ts = *reinterpret_cast<const float2*>(tg + base + sn);
            float2 td = *reinterpret_cast<const float2*>(tg + base + dn);
            float d0 = fabsf(ps.x - pd.x) - fabsf(ts.x - td.x);
            float d1 = fabsf(ps.y - pd.y) - fabsf(ts.y - td.y);
            s = fmaf(d0, d0, s);
            s = fmaf(d1, d1, s);
        }
    }
    for (int o = 32; o; o >>= 1) s += __shfl_xor(s, o);
    __shared__ float sv[4];
    if (lane == 0) sv[threadIdx.x >> 6] = s;
    __syncthreads();
    if (threadIdx.x == 0) ws[6144 + blockIdx.x] = sv[0] + sv[1] + sv[2] + sv[3];
}

__global__ __launch_bounds__(1024) void finalize_fb(const float* __restrict__ ws,
                                                    float* __restrict__ out) {
    int tid = threadIdx.x;
    float a = 0, bv = 0, sp = 0, cq = 0;
    for (int k = tid; k < 1536; k += 1024) { a += ws[k]; bv += ws[1536 + k]; }
    for (int k = tid; k < 2048; k += 1024) sp += ws[6144 + k];
    if (tid < BT * DD) {
        int bt = tid >> 1, par = tid & 1;
        float cs = 0;
        for (int part = 0; part < 8; ++part)
            cs += ws[3072 + ((bt * 8 + part) << 1) + par];
        cq = cs * cs;
    }
    for (int o = 32; o; o >>= 1) {
        a += __shfl_xor(a, o); bv += __shfl_xor(bv, o);
        sp += __shfl_xor(sp, o); cq += __shfl_xor(cq, o);
    }
    __shared__ float ra[16], rb[16], rs[16], rc[16];
    int wid = tid >> 6;
    if ((tid & 63) == 0) { ra[wid] = a; rb[wid] = bv; rs[wid] = sp; rc[wid] = cq; }
    __syncthreads();
    if (tid == 0) {
        float A = 0, B2 = 0, S = 0, C = 0;
        for (int k = 0; k < 16; k++) { A += ra[k]; B2 += rb[k]; S += rs[k]; C += rc[k]; }
        float mainl = A / (float)TOT;
        float temp  = B2 / (float)(BB * (TT - 1) * NN * DD);
        float spat  = S / ((float)BT * (float)EE * (float)DD);
        float cons  = C / (float)(BT * DD);
        out[0] = mainl + 0.1f * spat + 0.05f * temp + 0.02f * cons;
        out[1] = mainl; out[2] = spat; out[3] = temp; out[4] = cons;
    }
}

extern "C" void kernel_launch(void* const* d_in, const int* in_sizes, int n_in,
                              void* d_out, int out_size, void* d_ws, size_t ws_size,
                              hipStream_t stream) {
    const float* p  = (const float*)d_in[0];
    const float* tg = (const float*)d_in[1];
    const int*   ix = (const int*)d_in[2];
    float* out = (float*)d_out;
    char*  wsb = (char*)d_ws;
    float* ws  = (float*)d_ws;

    if (ws_size >= NEED) {
        prep_kernel<<<PREPG, 256, 0, stream>>>(p, tg, ix, wsb);
        spatial_kernel<<<SPATG, 1024, 0, stream>>>((const uint2*)(wsb + W2_BOFF),
                                                   (const uint2*)(wsb + EOFF_BOFF),
                                                   p, tg, ws);
        finalize_kernel<<<1, 1024, 0, stream>>>(ws, out);
    } else {
        stream_fb<<<1536, 256, 0, stream>>>(p, tg, ws);
        spatial_fb<<<2048, 256, 0, stream>>>(p, tg, ix, ws);
        finalize_fb<<<1, 1024, 0, stream>>>(ws, out);
    }
}

// Round 19
// 46.582 us; speedup vs baseline: 1.7441x; 1.0389x over previous
//
#include <hip/hip_runtime.h>
#include <hip/hip_fp16.h>

#define BB 16
#define TT 12
#define NN 10000
#define DD 2
#define EE 320000
#define BT 192              // BB*TT
#define TOT 3840000
#define SLICE 20000         // NN*DD

#define NCH 96              // chunks (2 bt-slots each); 96%8==0 -> XCD-pinnable
#define SLICES 14           // edge slices (1344+192 = 1536 = 3*512 block slots)
#define EPS 22858           // ceil(EE/SLICES), even; last slice short (guarded)
#define EPP 11429           // edge-pairs per slice (EPS/2)
#define SPATB (NCH*SLICES)  // 1344 gather blocks
#define SPATG (SPATB + BT)  // + 192 stream-role blocks (bid < BT)

// prep roles (pack | eoff only)
#define PACKB 942           // 157 node-groups * 6 slot-groups(32)
#define EOFFB 1250          // EE/256
#define PREPG (PACKB + EOFFB)

// ws float layout (fast path):
//   [0,192)       main partials (per bt)   [1536,1728) temporal partials (per bt)
//   [3072,3456)   cons sums (per bt*2+d)   [6144,6144+SPATB) spatial partials
// fallback: [0,1536) main, [1536,3072) temporal, [3072,6144) cons(8 parts), [6144..) spatial
#define EOFF_BOFF 32768
#define W2_BOFF   2623488   // 32768 + EE*8
#define NEED (W2_BOFF + (size_t)NCH * NN * 2 * 4)

typedef float v2f __attribute__((ext_vector_type(2)));
typedef _Float16 hv2 __attribute__((ext_vector_type(2)));

#if defined(__has_builtin)
#if __has_builtin(__builtin_amdgcn_fdot2)
#define HAVE_FDOT2 1
#endif
#if __has_builtin(__builtin_amdgcn_cvt_scalef32_pk_f16_fp8)
#define HAVE_SCALEF16 1
#endif
#endif

__device__ __forceinline__ __half2 pkh2(float a, float b) {
    auto t = __builtin_amdgcn_cvt_pkrtz(a, b);   // __fp16 ext_vector(2)
    return *reinterpret_cast<__half2*>(&t);
}
__device__ __forceinline__ float dot_acc(__half2 d, float acc) {
#ifdef HAVE_FDOT2
    hv2 dr = *reinterpret_cast<hv2*>(&d);
    return __builtin_amdgcn_fdot2(dr, dr, acc, false);
#else
    float2 f = __half22float2(d);
    return fmaf(f.y, f.y, fmaf(f.x, f.x, acc));
#endif
}
// one fp8-packed slot (u32 = p0,p1,t0,t1) both endpoints -> f32 acc
__device__ __forceinline__ void slot_acc(unsigned a, unsigned b, float& acc) {
#ifdef HAVE_SCALEF16
    auto pa = __builtin_amdgcn_cvt_scalef32_pk_f16_fp8(a, 1.0f, false);  // p0,p1
    auto ta = __builtin_amdgcn_cvt_scalef32_pk_f16_fp8(a, 1.0f, true);   // t0,t1
    auto pb = __builtin_amdgcn_cvt_scalef32_pk_f16_fp8(b, 1.0f, false);
    auto tb = __builtin_amdgcn_cvt_scalef32_pk_f16_fp8(b, 1.0f, true);
    __half2 hpa = *reinterpret_cast<__half2*>(&pa);
    __half2 hta = *reinterpret_cast<__half2*>(&ta);
    __half2 hpb = *reinterpret_cast<__half2*>(&pb);
    __half2 htb = *reinterpret_cast<__half2*>(&tb);
    __half2 d = __hsub2(__habs2(__hsub2(hpa, hpb)), __habs2(__hsub2(hta, htb)));
#else
    v2f ap = __builtin_amdgcn_cvt_pk_f32_fp8((int)a, false);
    v2f at = __builtin_amdgcn_cvt_pk_f32_fp8((int)a, true);
    v2f bp = __builtin_amdgcn_cvt_pk_f32_fp8((int)b, false);
    v2f bq = __builtin_amdgcn_cvt_pk_f32_fp8((int)b, true);
    __half2 d = __hsub2(__habs2(__hsub2(pkh2(ap[0], ap[1]), pkh2(bp[0], bp[1]))),
                        __habs2(__hsub2(pkh2(at[0], at[1]), pkh2(bq[0], bq[1]))));
#endif
    acc = dot_acc(d, acc);
}
// one edge (both chunk slots) from its packed offsets
__device__ __forceinline__ void edge_acc(const char* ndb, unsigned so, unsigned do_,
                                         float& a0, float& a1) {
    uint2 A = *(const uint2*)(ndb + so);
    uint2 B = *(const uint2*)(ndb + do_);
    slot_acc(A.x, B.x, a0);
    slot_acc(A.y, B.y, a1);
}

// ---------------- prep: pack(fp8, chunk-major) | eoff (byte-prescaled) ------
__global__ __launch_bounds__(256) void prep_kernel(const float* __restrict__ p,
                                                   const float* __restrict__ tg,
                                                   const int* __restrict__ idx,
                                                   char* __restrict__ wsb) {
    int g = blockIdx.x;
    if (g < PACKB) {                                    // ---- pack role
        __shared__ unsigned tile[64][33];
        int ng = g / 6, cg = g % 6;                     // 64-node group, 32-slot group
        int n0 = ng * 64;
        int ln = threadIdx.x & 63, r = threadIdx.x >> 6;
        int n = n0 + ln;
        if (n < NN) {
            for (int sl = r; sl < 32; sl += 4) {
                int bt = cg * 32 + sl;
                size_t e = (size_t)bt * SLICE + (size_t)n * 2;
                float2 pv = *reinterpret_cast<const float2*>(p + e);
                float2 tv = *reinterpret_cast<const float2*>(tg + e);
                int pk = __builtin_amdgcn_cvt_pk_fp8_f32(pv.x, pv.y, 0, false);
                pk = __builtin_amdgcn_cvt_pk_fp8_f32(tv.x, tv.y, pk, true);
                tile[ln][sl] = (unsigned)pk;
            }
        }
        __syncthreads();
        unsigned* w2c = (unsigned*)(wsb + W2_BOFF);
        for (int f = threadIdx.x; f < 2048; f += 256) {
            int c2 = f >> 7, j2 = f & 127;
            int nn2 = j2 >> 1, k2 = j2 & 1;
            int n2 = n0 + nn2;
            if (n2 < NN) {
                int c = cg * 16 + c2;
                w2c[((unsigned)(c * NN + n2) << 1) + k2] = tile[nn2][c2 * 2 + k2];
            }
        }
    } else {                                            // ---- eoff role
        int e = (g - PACKB) * 256 + threadIdx.x;
        if (e < EE) {
            uint2* eoff = (uint2*)(wsb + EOFF_BOFF);
            eoff[e] = make_uint2((unsigned)idx[e] * 8u,          // LDS byte offsets
                                 (unsigned)idx[EE + e] * 8u);
        }
    }
}

// ---------------- spatial: stream blocks first, then gather blocks ----------
__global__ __launch_bounds__(1024, 8) void spatial_kernel(const uint2* __restrict__ w2c2,
                                                          const uint2* __restrict__ eoff,
                                                          const float* __restrict__ p,
                                                          const float* __restrict__ tg,
                                                          float* __restrict__ ws) {
    __shared__ uint2 nd[NN];            // 80,000 B (gather role)
    __shared__ float red[64];
    int bid = blockIdx.x;
    int tid = threadIdx.x;

    if (bid < BT) {                     // ---- stream role: one bt per block
        int bt = bid;
        size_t base = (size_t)bt * SLICE;
        bool inner = (bt % TT) < TT - 1;
        const float2* p2  = (const float2*)(p + base);
        const float2* t2  = (const float2*)(tg + base);
        const float2* pn2 = (const float2*)(p + base + SLICE);
        const float2* tn2 = (const float2*)(tg + base + SLICE);
        float m = 0.f, w = 0.f, cx = 0.f, cy = 0.f;
        for (int j = tid; j < NN; j += 1024) {
            float2 pv = p2[j], tv = t2[j];
            m += fabsf(pv.x - tv.x) + fabsf(pv.y - tv.y);
            cx += pv.x - tv.x;
            cy += pv.y - tv.y;
            if (inner) {
                float2 pn = pn2[j], tn = tn2[j];
                float d0 = (pn.x - pv.x) - (tn.x - tv.x);
                float d1 = (pn.y - pv.y) - (tn.y - tv.y);
                w = fmaf(d0, d0, w);
                w = fmaf(d1, d1, w);
            }
        }
        for (int o = 32; o; o >>= 1) {
            m += __shfl_xor(m, o); w += __shfl_xor(w, o);
            cx += __shfl_xor(cx, o); cy += __shfl_xor(cy, o);
        }
        int wid = tid >> 6;
        if ((tid & 63) == 0) {
            red[wid] = m; red[16 + wid] = w; red[32 + wid] = cx; red[48 + wid] = cy;
        }
        __syncthreads();
        if (tid == 0) {
            float M = 0, W = 0, CX = 0, CY = 0;
            for (int k = 0; k < 16; ++k) {
                M += red[k]; W += red[16 + k]; CX += red[32 + k]; CY += red[48 + k];
            }
            ws[bt] = M;
            ws[1536 + bt] = W;
            ws[3072 + 2 * bt] = CX;
            ws[3072 + 2 * bt + 1] = CY;
        }
        return;
    }

    // ---- gather role
    int gb = bid - BT;
    int c = gb % NCH;                   // chunk; same-c blocks land on XCD c%8
    int s = gb / NCH;                   // edge slice
    const uint4* src4 = (const uint4*)(w2c2 + (size_t)c * NN);
    uint4* nd4 = (uint4*)nd;
    for (int i = tid; i < NN / 2; i += 1024)
        nd4[i] = src4[i];
    __syncthreads();

    const char* ndb = (const char*)nd;
    const uint4* eoff4 = (const uint4*)eoff;    // 2 edges per uint4
    int i = s * EPP + tid;
    int pend = (s + 1) * EPP;
    if (pend > EE / 2) pend = EE / 2;
    float acc0 = 0.f, acc1 = 0.f;
    while (i + 1024 < pend) {           // 4 edges per iter (2 coalesced uint4 loads)
        uint4 q1 = eoff4[i];
        uint4 q2 = eoff4[i + 1024];
        edge_acc(ndb, q1.x, q1.y, acc0, acc1);
        edge_acc(ndb, q1.z, q1.w, acc0, acc1);
        edge_acc(ndb, q2.x, q2.y, acc0, acc1);
        edge_acc(ndb, q2.z, q2.w, acc0, acc1);
        i += 2048;
    }
    if (i < pend) {                     // tail: single uint4 (2 edges)
        uint4 q = eoff4[i];
        edge_acc(ndb, q.x, q.y, acc0, acc1);
        edge_acc(ndb, q.z, q.w, acc0, acc1);
    }
    float acc = acc0 + acc1;
    for (int o = 32; o; o >>= 1) acc += __shfl_xor(acc, o);
    if ((tid & 63) == 0) red[tid >> 6] = acc;
    __syncthreads();
    if (tid == 0) {
        float t = 0.f;
        for (int k = 0; k < 16; ++k) t += red[k];
        ws[6144 + gb] = t;
    }
}

// ---------------- finalize (fast path, compact layout) ----------------------
__global__ __launch_bounds__(1024) void finalize_kernel(const float* __restrict__ ws,
                                                        float* __restrict__ out) {
    int tid = threadIdx.x;
    float a = 0, bv = 0, sp = 0, cq = 0;
    if (tid < BT) { a = ws[tid]; bv = ws[1536 + tid]; }
    for (int k = tid; k < SPATB; k += 1024) sp += ws[6144 + k];
    if (tid < BT * DD) { float cs = ws[3072 + tid]; cq = cs * cs; }
    for (int o = 32; o; o >>= 1) {
        a += __shfl_xor(a, o); bv += __shfl_xor(bv, o);
        sp += __shfl_xor(sp, o); cq += __shfl_xor(cq, o);
    }
    __shared__ float ra[16], rb[16], rs[16], rc[16];
    int wid = tid >> 6;
    if ((tid & 63) == 0) { ra[wid] = a; rb[wid] = bv; rs[wid] = sp; rc[wid] = cq; }
    __syncthreads();
    if (tid == 0) {
        float A = 0, B2 = 0, S = 0, C = 0;
        for (int k = 0; k < 16; k++) { A += ra[k]; B2 += rb[k]; S += rs[k]; C += rc[k]; }
        float mainl = A / (float)TOT;
        float temp  = B2 / (float)(BB * (TT - 1) * NN * DD);
        float spat  = S / ((float)BT * (float)EE * (float)DD);
        float cons  = C / (float)(BT * DD);
        out[0] = mainl + 0.1f * spat + 0.05f * temp + 0.02f * cons;
        out[1] = mainl; out[2] = spat; out[3] = temp; out[4] = cons;
    }
}

// ================= fallback path (ws too small) =============================
__global__ __launch_bounds__(256) void stream_fb(const float* __restrict__ p,
                                                 const float* __restrict__ tg,
                                                 float* __restrict__ ws) {
    int b = blockIdx.x;
    int bt = b >> 3, part = b & 7;
    int tt = bt % TT;
    size_t base = (size_t)bt * SLICE;
    bool inner = (tt < TT - 1);
    float m = 0.f, w = 0.f, c = 0.f;
    int j0 = part * 2500;
    for (int j = j0 + threadIdx.x; j < j0 + 2500; j += 256) {
        size_t jj = base + j;
        float pv = p[jj], tv = tg[jj];
        m += fabsf(pv - tv);
        c += pv - tv;
        if (inner) {
            float pn = p[jj + SLICE], tn = tg[jj + SLICE];
            float dd = (pn - pv) - (tn - tv);
            w += dd * dd;
        }
    }
    for (int o = 32; o >= 2; o >>= 1) {
        m += __shfl_xor(m, o); w += __shfl_xor(w, o); c += __shfl_xor(c, o);
    }
    m += __shfl_xor(m, 1);
    w += __shfl_xor(w, 1);
    __shared__ float sm[4], sw[4], s0[4], s1[4];
    int wid = threadIdx.x >> 6, lane = threadIdx.x & 63;
    if (lane == 0) { sm[wid] = m; sw[wid] = w; s0[wid] = c; }
    if (lane == 1) { s1[wid] = c; }
    __syncthreads();
    if (threadIdx.x == 0) {
        float a = 0, bv = 0, c0 = 0, c1 = 0;
        for (int k = 0; k < 4; k++) { a += sm[k]; bv += sw[k]; c0 += s0[k]; c1 += s1[k]; }
        ws[b] = a; ws[1536 + b] = bv;
        ws[3072 + 2 * b] = c0; ws[3072 + 2 * b + 1] = c1;
    }
}

__global__ __launch_bounds__(256) void spatial_fb(const float* __restrict__ p,
                                                  const float* __restrict__ tg,
                                                  const int* __restrict__ idx,
                                                  float* __restrict__ ws) {
    int lane = threadIdx.x & 63;
    int wave = (blockIdx.x * 256 + threadIdx.x) >> 6;
    float s = 0.f;
    for (int e = wave; e < EE; e += 2048 * 4) {
        int sn = idx[e] * DD, dn = idx[EE + e] * DD;
        for (int bt = lane; bt < BT; bt += 64) {
            size_t base = (size_t)bt * SLICE;
            float2 ps = *reinterpret_cast<const float2*>(p + base + sn);
            float2 pd = *reinterpret_cast<const float2*>(p + base + dn);
            float2 ts = *reinterpret_cast<const float2*>(tg + base + sn);
            float2 td = *reinterpret_cast<const float2*>(tg + base + dn);
            float d0 = fabsf(ps.x - pd.x) - fabsf(ts.x - td.x);
            float d1 = fabsf(ps.y - pd.y) - fabsf(ts.y - td.y);
            s = fmaf(d0, d0, s);
            s = fmaf(d1, d1, s);
        }
    }
    for (int o = 32; o; o >>= 1) s += __shfl_xor(s, o);
    __shared__ float sv[4];
    if (lane == 0) sv[threadIdx.x >> 6] = s;
    __syncthreads();
    if (threadIdx.x == 0) ws[6144 + blockIdx.x] = sv[0] + sv[1] + sv[2] + sv[3];
}

__global__ __launch_bounds__(1024) void finalize_fb(const float* __restrict__ ws,
                                                    float* __restrict__ out) {
    int tid = threadIdx.x;
    float a = 0, bv = 0, sp = 0, cq = 0;
    for (int k = tid; k < 1536; k += 1024) { a += ws[k]; bv += ws[1536 + k]; }
    for (int k = tid; k < 2048; k += 1024) sp += ws[6144 + k];
    if (tid < BT * DD) {
        int bt = tid >> 1, par = tid & 1;
        float cs = 0;
        for (int part = 0; part < 8; ++part)
            cs += ws[3072 + ((bt * 8 + part) << 1) + par];
        cq = cs * cs;
    }
    for (int o = 32; o; o >>= 1) {
        a += __shfl_xor(a, o); bv += __shfl_xor(bv, o);
        sp += __shfl_xor(sp, o); cq += __shfl_xor(cq, o);
    }
    __shared__ float ra[16], rb[16], rs[16], rc[16];
    int wid = tid >> 6;
    if ((tid & 63) == 0) { ra[wid] = a; rb[wid] = bv; rs[wid] = sp; rc[wid] = cq; }
    __syncthreads();
    if (tid == 0) {
        float A = 0, B2 = 0, S = 0, C = 0;
        for (int k = 0; k < 16; k++) { A += ra[k]; B2 += rb[k]; S += rs[k]; C += rc[k]; }
        float mainl = A / (float)TOT;
        float temp  = B2 / (float)(BB * (TT - 1) * NN * DD);
        float spat  = S / ((float)BT * (float)EE * (float)DD);
        float cons  = C / (float)(BT * DD);
        out[0] = mainl + 0.1f * spat + 0.05f * temp + 0.02f * cons;
        out[1] = mainl; out[2] = spat; out[3] = temp; out[4] = cons;
    }
}

extern "C" void kernel_launch(void* const* d_in, const int* in_sizes, int n_in,
                              void* d_out, int out_size, void* d_ws, size_t ws_size,
                              hipStream_t stream) {
    const float* p  = (const float*)d_in[0];
    const float* tg = (const float*)d_in[1];
    const int*   ix = (const int*)d_in[2];
    float* out = (float*)d_out;
    char*  wsb = (char*)d_ws;
    float* ws  = (float*)d_ws;

    if (ws_size >= NEED) {
        prep_kernel<<<PREPG, 256, 0, stream>>>(p, tg, ix, wsb);
        spatial_kernel<<<SPATG, 1024, 0, stream>>>((const uint2*)(wsb + W2_BOFF),
                                                   (const uint2*)(wsb + EOFF_BOFF),
                                                   p, tg, ws);
        finalize_kernel<<<1, 1024, 0, stream>>>(ws, out);
    } else {
        stream_fb<<<1536, 256, 0, stream>>>(p, tg, ws);
        spatial_fb<<<2048, 256, 0, stream>>>(p, tg, ix, ws);
        finalize_fb<<<1, 1024, 0, stream>>>(ws, out);
    }
}